// Round 1
// baseline (3582.776 us; speedup 1.0000x reference)
//
#include <hip/hip_runtime.h>
#include <hip/hip_bf16.h>

#define LAYERS 4
#define H 1024
#define NH 16
#define KVH 4
#define HD 64
#define KVD 256
#define FF 4096
#define VOC 32000
#define BB 2
#define SS 2048
#define MROWS (BB*SS)

typedef __attribute__((ext_vector_type(4))) float f32x4;
typedef __attribute__((ext_vector_type(8))) short short8;
typedef __attribute__((ext_vector_type(4))) unsigned int u32x4;
typedef __attribute__((ext_vector_type(4))) unsigned short u16x4;

__device__ inline unsigned short f2bf(float f){
  union { float f; unsigned u; } v; v.f = f;
  return (unsigned short)((v.u + 0x7FFFu + ((v.u >> 16) & 1u)) >> 16);
}

// ---------------- embedding: x = tok_emb[id] + pos_emb[s] ----------------
__global__ __launch_bounds__(256) void embed_kernel(const int* __restrict__ ids,
    const float* __restrict__ tok, const float* __restrict__ pos, float* __restrict__ x)
{
  int row = blockIdx.x;              // b*S + s
  int s = row & (SS-1);
  int id = ids[row];
  int t = threadIdx.x;
  f32x4 a = *(const f32x4*)&tok[(size_t)id*H + t*4];
  f32x4 p = *(const f32x4*)&pos[(size_t)s*H + t*4];
  *(f32x4*)&x[(size_t)row*H + t*4] = a + p;
}

// ---------------- layernorm: f32 in -> bf16 out ----------------
__global__ __launch_bounds__(256) void ln_kernel(const float* __restrict__ x,
    const float* __restrict__ g, const float* __restrict__ b, unsigned short* __restrict__ out)
{
  int row = blockIdx.x;
  int t = threadIdx.x;
  const float* xr = x + (size_t)row*H;
  f32x4 v = *(const f32x4*)&xr[t*4];
  float s  = v[0]+v[1]+v[2]+v[3];
  float s2 = v[0]*v[0]+v[1]*v[1]+v[2]*v[2]+v[3]*v[3];
  #pragma unroll
  for (int off=1; off<64; off<<=1){ s += __shfl_xor(s,off); s2 += __shfl_xor(s2,off); }
  __shared__ float red[8];
  int w = t>>6;
  if ((t&63)==0){ red[w]=s; red[4+w]=s2; }
  __syncthreads();
  float S1 = red[0]+red[1]+red[2]+red[3];
  float S2 = red[4]+red[5]+red[6]+red[7];
  float mean = S1 * (1.0f/H);
  float var  = S2 * (1.0f/H) - mean*mean;
  float rs = rsqrtf(var + 1e-5f);
  u16x4 o;
  #pragma unroll
  for (int i=0;i<4;i++) o[i] = f2bf((v[i]-mean)*rs*g[t*4+i] + b[t*4+i]);
  *(u16x4*)&out[(size_t)row*H + t*4] = o;
}

// ---------------- GEMM: C(MxN) = A(MxK bf16) @ B(KxN f32->bf16) ----------------
// EPI: 0 = +bias -> bf16 | 1 = +bias+residual -> f32 | 2 = +bias+gelu -> bf16 | 3 = plain -> f32
template<int EPI>
__global__ __launch_bounds__(256) void gemm_kernel(
    const unsigned short* __restrict__ A, const float* __restrict__ Bw,
    const float* __restrict__ bias, const float* __restrict__ res,
    float* __restrict__ outf, unsigned short* __restrict__ outb, int N, int K)
{
  __shared__ unsigned short As[128][40];
  __shared__ unsigned short Bs[128][40];   // transposed: [n][k]
  int m0 = blockIdx.y*128, n0 = blockIdx.x*128;
  int tid = threadIdx.x;
  int lane = tid & 63, w = tid >> 6;
  int wr = (w>>1)*64, wc = (w&1)*64;
  int fr = lane & 15, fo = (lane>>4)*8;
  f32x4 acc[4][4] = {};
  int ar = tid>>1,    ac = (tid&1)*16;     // A stage: row, col
  int bk = (tid&7)*4, bn = (tid>>3)*4;     // B stage: 4 k-rows x 4 n-cols
  const unsigned short* ap = A + (size_t)(m0+ar)*K + ac;
  const float* bp = Bw + (size_t)bk*N + n0 + bn;
  for (int k0=0; k0<K; k0+=32){
    u32x4 av0 = *(const u32x4*)(ap);
    u32x4 av1 = *(const u32x4*)(ap+8);
    f32x4 b0 = *(const f32x4*)(bp);
    f32x4 b1 = *(const f32x4*)(bp+N);
    f32x4 b2 = *(const f32x4*)(bp+2*(size_t)N);
    f32x4 b3 = *(const f32x4*)(bp+3*(size_t)N);
    ap += 32; bp += (size_t)32*N;
    __syncthreads();
    *(u32x4*)&As[ar][ac]   = av0;
    *(u32x4*)&As[ar][ac+8] = av1;
    #pragma unroll
    for (int j=0;j<4;j++){
      u16x4 cv; cv[0]=f2bf(b0[j]); cv[1]=f2bf(b1[j]); cv[2]=f2bf(b2[j]); cv[3]=f2bf(b3[j]);
      *(u16x4*)&Bs[bn+j][bk] = cv;
    }
    __syncthreads();
    short8 af[4], bfr[4];
    #pragma unroll
    for (int mi=0;mi<4;mi++) af[mi]  = *(const short8*)&As[wr+mi*16+fr][fo];
    #pragma unroll
    for (int ni=0;ni<4;ni++) bfr[ni] = *(const short8*)&Bs[wc+ni*16+fr][fo];
    #pragma unroll
    for (int mi=0;mi<4;mi++)
      #pragma unroll
      for (int ni=0;ni<4;ni++)
        acc[mi][ni] = __builtin_amdgcn_mfma_f32_16x16x32_bf16(af[mi], bfr[ni], acc[mi][ni], 0,0,0);
  }
  int rb = (lane>>4)*4;
  #pragma unroll
  for (int mi=0;mi<4;mi++)
    #pragma unroll
    for (int ni=0;ni<4;ni++){
      int col = n0 + wc + ni*16 + fr;
      float bi = (EPI==3) ? 0.0f : bias[col];
      #pragma unroll
      for (int r=0;r<4;r++){
        int row = m0 + wr + mi*16 + rb + r;
        float vv = acc[mi][ni][r] + bi;
        size_t idx = (size_t)row*N + col;
        if (EPI==1)      outf[idx] = vv + res[idx];
        else if (EPI==2) outb[idx] = f2bf(0.5f*vv*(1.0f+erff(vv*0.70710678118f)));
        else if (EPI==0) outb[idx] = f2bf(vv);
        else             outf[idx] = vv;
      }
    }
}

// ---------------- flash attention (full, additive key mask) ----------------
// 1 wave per block; 16 q-rows per block; iterate keys in chunks of 32.
__global__ __launch_bounds__(64) void attn_kernel(
    const unsigned short* __restrict__ q, const unsigned short* __restrict__ k,
    const unsigned short* __restrict__ v, const float* __restrict__ mask,
    unsigned short* __restrict__ o)
{
  __shared__ unsigned short P[16][40];
  int lane = threadIdx.x;
  int bid = blockIdx.x;
  int qt = bid & (SS/16 - 1);
  int h  = (bid >> 7) & (NH-1);
  int b  = bid >> 11;
  int g  = h >> 2;                 // kv head
  int qcol = h*HD, kcol = g*HD;
  int fr = lane & 15, fo = (lane>>4)*8;
  const unsigned short* qrow = q + (size_t)(b*SS + qt*16 + fr)*H + qcol;
  short8 a0 = *(const short8*)(qrow + fo);
  short8 a1 = *(const short8*)(qrow + 32 + fo);
  f32x4 oacc[4] = {};
  float m[4]    = {-1e30f,-1e30f,-1e30f,-1e30f};
  float lsum[4] = {0.f,0.f,0.f,0.f};
  const float scale = 0.125f;
  for (int kc=0; kc<SS; kc+=32){
    f32x4 sf[2] = {};
    #pragma unroll
    for (int f=0; f<2; f++){
      const unsigned short* krow = k + (size_t)(b*SS + kc + f*16 + fr)*KVD + kcol;
      short8 kb0 = *(const short8*)(krow + fo);
      short8 kb1 = *(const short8*)(krow + 32 + fo);
      sf[f] = __builtin_amdgcn_mfma_f32_16x16x32_bf16(a0, kb0, sf[f],0,0,0);
      sf[f] = __builtin_amdgcn_mfma_f32_16x16x32_bf16(a1, kb1, sf[f],0,0,0);
    }
    float mk0 = mask[b*SS + kc + fr];
    float mk1 = mask[b*SS + kc + 16 + fr];
    float alpha[4];
    #pragma unroll
    for (int r=0;r<4;r++){
      sf[0][r] = sf[0][r]*scale + mk0;
      sf[1][r] = sf[1][r]*scale + mk1;
      float c = fmaxf(sf[0][r], sf[1][r]);
      #pragma unroll
      for (int off=1; off<16; off<<=1) c = fmaxf(c, __shfl_xor(c, off));
      float mn = fmaxf(m[r], c);
      alpha[r] = __expf(m[r]-mn);
      m[r] = mn;
    }
    int prow = (lane>>4)*4;
    #pragma unroll
    for (int r=0;r<4;r++){
      sf[0][r] = __expf(sf[0][r]-m[r]);
      sf[1][r] = __expf(sf[1][r]-m[r]);
      float ps = sf[0][r]+sf[1][r];
      #pragma unroll
      for (int off=1; off<16; off<<=1) ps += __shfl_xor(ps, off);
      lsum[r] = lsum[r]*alpha[r] + ps;
      oacc[0][r]*=alpha[r]; oacc[1][r]*=alpha[r]; oacc[2][r]*=alpha[r]; oacc[3][r]*=alpha[r];
      P[prow+r][fr]    = f2bf(sf[0][r]);
      P[prow+r][16+fr] = f2bf(sf[1][r]);
    }
    __syncthreads();
    short8 pa = *(const short8*)&P[fr][fo];
    const unsigned short* vbase = v + (size_t)(b*SS + kc + fo)*KVD + kcol + fr;
    #pragma unroll
    for (int dc=0; dc<4; dc++){
      union { unsigned short u[8]; short8 s; } vu;
      #pragma unroll
      for (int j=0;j<8;j++) vu.u[j] = vbase[(size_t)j*KVD + dc*16];
      oacc[dc] = __builtin_amdgcn_mfma_f32_16x16x32_bf16(pa, vu.s, oacc[dc],0,0,0);
    }
    __syncthreads();
  }
  #pragma unroll
  for (int dc=0;dc<4;dc++)
    #pragma unroll
    for (int r=0;r<4;r++){
      float val = oacc[dc][r] / lsum[r];
      int row = qt*16 + (lane>>4)*4 + r;
      o[(size_t)(b*SS + row)*H + qcol + dc*16 + fr] = f2bf(val);
    }
}

extern "C" void kernel_launch(void* const* d_in, const int* in_sizes, int n_in,
                              void* d_out, int out_size, void* d_ws, size_t ws_size,
                              hipStream_t stream)
{
  const int*   ids  = (const int*)  d_in[0];
  const float* mask = (const float*)d_in[1];
  const float* tok  = (const float*)d_in[2];
  const float* pos  = (const float*)d_in[3];
  const float* Wq   = (const float*)d_in[4];
  const float* bq   = (const float*)d_in[5];
  const float* Wk   = (const float*)d_in[6];
  const float* bk   = (const float*)d_in[7];
  const float* Wv   = (const float*)d_in[8];
  const float* bv   = (const float*)d_in[9];
  const float* Wo   = (const float*)d_in[10];
  const float* bo   = (const float*)d_in[11];
  const float* W1   = (const float*)d_in[12];
  const float* b1   = (const float*)d_in[13];
  const float* W2   = (const float*)d_in[14];
  const float* b2   = (const float*)d_in[15];
  const float* ln1g = (const float*)d_in[16];
  const float* ln1b = (const float*)d_in[17];
  const float* ln2g = (const float*)d_in[18];
  const float* ln2b = (const float*)d_in[19];
  const float* lnfg = (const float*)d_in[20];
  const float* lnfb = (const float*)d_in[21];
  const float* Wh   = (const float*)d_in[22];
  float* out = (float*)d_out;

  char* ws = (char*)d_ws;
  float*          x  = (float*)ws;          ws += (size_t)MROWS*H*4;
  unsigned short* hb = (unsigned short*)ws; ws += (size_t)MROWS*H*2;
  unsigned short* qb = (unsigned short*)ws; ws += (size_t)MROWS*H*2;
  unsigned short* kb = (unsigned short*)ws; ws += (size_t)MROWS*KVD*2;
  unsigned short* vb = (unsigned short*)ws; ws += (size_t)MROWS*KVD*2;
  unsigned short* ob = (unsigned short*)ws; ws += (size_t)MROWS*H*2;
  unsigned short* f1 = (unsigned short*)ws; ws += (size_t)MROWS*FF*2;

  embed_kernel<<<MROWS, 256, 0, stream>>>(ids, tok, pos, x);
  for (int l=0; l<LAYERS; l++){
    ln_kernel<<<MROWS,256,0,stream>>>(x, ln1g + l*H, ln1b + l*H, hb);
    gemm_kernel<0><<<dim3(H/128,   MROWS/128),256,0,stream>>>(hb, Wq + (size_t)l*H*H,   bq + l*H,   nullptr, nullptr, qb, H,   H);
    gemm_kernel<0><<<dim3(KVD/128, MROWS/128),256,0,stream>>>(hb, Wk + (size_t)l*H*KVD, bk + l*KVD, nullptr, nullptr, kb, KVD, H);
    gemm_kernel<0><<<dim3(KVD/128, MROWS/128),256,0,stream>>>(hb, Wv + (size_t)l*H*KVD, bv + l*KVD, nullptr, nullptr, vb, KVD, H);
    attn_kernel<<<BB*NH*(SS/16), 64, 0, stream>>>(qb, kb, vb, mask, ob);
    gemm_kernel<1><<<dim3(H/128,   MROWS/128),256,0,stream>>>(ob, Wo + (size_t)l*H*H,   bo + l*H,   x, x, nullptr, H, H);
    ln_kernel<<<MROWS,256,0,stream>>>(x, ln2g + l*H, ln2b + l*H, hb);
    gemm_kernel<2><<<dim3(FF/128,  MROWS/128),256,0,stream>>>(hb, W1 + (size_t)l*H*FF,  b1 + l*FF,  nullptr, nullptr, f1, FF, H);
    gemm_kernel<1><<<dim3(H/128,   MROWS/128),256,0,stream>>>(f1, W2 + (size_t)l*FF*H,  b2 + l*H,   x, x, nullptr, H, FF);
  }
  ln_kernel<<<MROWS,256,0,stream>>>(x, lnfg, lnfb, hb);
  gemm_kernel<3><<<dim3(VOC/128, MROWS/128),256,0,stream>>>(hb, Wh, nullptr, nullptr, out, nullptr, VOC, H);
}

// Round 2
// 2440.291 us; speedup vs baseline: 1.4682x; 1.4682x over previous
//
#include <hip/hip_runtime.h>
#include <hip/hip_bf16.h>

#define LAYERS 4
#define H 1024
#define NH 16
#define KVH 4
#define HD 64
#define KVD 256
#define FF 4096
#define VOC 32000
#define BB 2
#define SS 2048
#define MROWS (BB*SS)

typedef __attribute__((ext_vector_type(4))) float f32x4;
typedef __attribute__((ext_vector_type(8))) short short8;
typedef __attribute__((ext_vector_type(4))) unsigned short u16x4;

__device__ inline unsigned short f2bf(float f){
  union { float f; unsigned u; } v; v.f = f;
  return (unsigned short)((v.u + 0x7FFFu + ((v.u >> 16) & 1u)) >> 16);
}

// ---------------- embedding: x = tok_emb[id] + pos_emb[s] ----------------
__global__ __launch_bounds__(256) void embed_kernel(const int* __restrict__ ids,
    const float* __restrict__ tok, const float* __restrict__ pos, float* __restrict__ x)
{
  int row = blockIdx.x;
  int s = row & (SS-1);
  int id = ids[row];
  int t = threadIdx.x;
  f32x4 a = *(const f32x4*)&tok[(size_t)id*H + t*4];
  f32x4 p = *(const f32x4*)&pos[(size_t)s*H + t*4];
  *(f32x4*)&x[(size_t)row*H + t*4] = a + p;
}

// ---------------- layernorm: f32 in -> bf16 out ----------------
__global__ __launch_bounds__(256) void ln_kernel(const float* __restrict__ x,
    const float* __restrict__ g, const float* __restrict__ b, unsigned short* __restrict__ out)
{
  int row = blockIdx.x;
  int t = threadIdx.x;
  const float* xr = x + (size_t)row*H;
  f32x4 v = *(const f32x4*)&xr[t*4];
  float s  = v[0]+v[1]+v[2]+v[3];
  float s2 = v[0]*v[0]+v[1]*v[1]+v[2]*v[2]+v[3]*v[3];
  #pragma unroll
  for (int off=1; off<64; off<<=1){ s += __shfl_xor(s,off); s2 += __shfl_xor(s2,off); }
  __shared__ float red[8];
  int w = t>>6;
  if ((t&63)==0){ red[w]=s; red[4+w]=s2; }
  __syncthreads();
  float S1 = red[0]+red[1]+red[2]+red[3];
  float S2 = red[4]+red[5]+red[6]+red[7];
  float mean = S1 * (1.0f/H);
  float var  = S2 * (1.0f/H) - mean*mean;
  float rs = rsqrtf(var + 1e-5f);
  u16x4 o;
  #pragma unroll
  for (int i=0;i<4;i++) o[i] = f2bf((v[i]-mean)*rs*g[t*4+i] + b[t*4+i]);
  *(u16x4*)&out[(size_t)row*H + t*4] = o;
}

// ---------------- weight convert+transpose: f32 [K][N] -> bf16 [N][K] ----------------
__global__ __launch_bounds__(256) void convT_kernel(const float* __restrict__ in,
    unsigned short* __restrict__ out, int K, int N)
{
  __shared__ float t[32][33];
  size_t off = (size_t)blockIdx.z * K * N;
  in += off; out += off;
  int n0 = blockIdx.x*32, k0 = blockIdx.y*32;
  int x = threadIdx.x & 31, y = threadIdx.x >> 5;   // y 0..7
  #pragma unroll
  for (int j=0;j<4;j++) t[y+j*8][x] = in[(size_t)(k0+y+j*8)*N + n0 + x];
  __syncthreads();
  int x2 = threadIdx.x & 15, y2 = threadIdx.x >> 4; // y2 0..15
  #pragma unroll
  for (int j=0;j<2;j++){
    int n = y2 + j*16;
    unsigned lo = f2bf(t[x2*2][n]);
    unsigned hi = f2bf(t[x2*2+1][n]);
    *(unsigned*)&out[(size_t)(n0+n)*K + k0 + x2*2] = lo | (hi<<16);
  }
}

// ---------------- GEMM: C(MxN) = A(M x K bf16) @ Bt(N x K bf16)^T ----------------
// m97 structure: 128x128 tile, BK=32, global_load_lds width 16, 16 MFMA/K-step.
// EPI: 0 = +bias -> bf16 | 1 = +bias+residual -> f32 | 2 = +bias+gelu -> bf16
//      3 = plain -> f32  | 4 = +bias -> bf16 TRANSPOSED out (out[col*MROWS+row])
template<int EPI>
__global__ __launch_bounds__(256) void gemm_bt(
    const unsigned short* __restrict__ A, const unsigned short* __restrict__ Bt,
    const float* __restrict__ bias, const float* __restrict__ res,
    float* __restrict__ outf, unsigned short* __restrict__ outb, int N, int K)
{
  __shared__ unsigned short As[128*32];
  __shared__ unsigned short Bs[128*32];
  int m0 = blockIdx.x*128, n0 = blockIdx.y*128;   // x = M (fast) so blocks share B panel
  int tid = threadIdx.x;
  int lane = tid & 63, w = tid >> 6;
  int wr = (w>>1)*64, wc = (w&1)*64;
  int fr = lane & 15, fq = lane >> 4;
  f32x4 acc[4][4] = {};
  int srow = lane >> 2;          // 0..15
  int scol = (lane & 3) * 8;     // element col (16B)
  const unsigned short* a0 = A  + (size_t)m0*K + scol;
  const unsigned short* b0 = Bt + (size_t)n0*K + scol;
  for (int k0 = 0; k0 < K; k0 += 32){
    __syncthreads();   // previous tile's frag reads complete before overwrite
    #pragma unroll
    for (int c = 0; c < 2; c++){
      int ch = w*2 + c;                 // 0..7
      int row = ch*16 + srow;           // 0..127
      __builtin_amdgcn_global_load_lds(
        (const __attribute__((address_space(1))) void*)(a0 + (size_t)row*K + k0),
        (__attribute__((address_space(3))) void*)(As + ch*512), 16, 0, 0);
      __builtin_amdgcn_global_load_lds(
        (const __attribute__((address_space(1))) void*)(b0 + (size_t)row*K + k0),
        (__attribute__((address_space(3))) void*)(Bs + ch*512), 16, 0, 0);
    }
    __syncthreads();   // vmcnt(0) drain: staged data visible
    short8 af[4], bf[4];
    #pragma unroll
    for (int mi=0;mi<4;mi++) af[mi] = *(const short8*)&As[(wr+mi*16+fr)*32 + fq*8];
    #pragma unroll
    for (int ni=0;ni<4;ni++) bf[ni] = *(const short8*)&Bs[(wc+ni*16+fr)*32 + fq*8];
    #pragma unroll
    for (int mi=0;mi<4;mi++)
      #pragma unroll
      for (int ni=0;ni<4;ni++)
        acc[mi][ni] = __builtin_amdgcn_mfma_f32_16x16x32_bf16(af[mi], bf[ni], acc[mi][ni], 0,0,0);
  }
  #pragma unroll
  for (int mi=0;mi<4;mi++)
    #pragma unroll
    for (int ni=0;ni<4;ni++){
      int col = n0 + wc + ni*16 + fr;
      float bi = (EPI==3) ? 0.0f : bias[col];
      #pragma unroll
      for (int r=0;r<4;r++){
        int row = m0 + wr + mi*16 + fq*4 + r;
        float vv = acc[mi][ni][r] + bi;
        size_t idx = (size_t)row*N + col;
        if (EPI==1)      outf[idx] = vv + res[idx];
        else if (EPI==2) outb[idx] = f2bf(0.5f*vv*(1.0f+erff(vv*0.70710678118f)));
        else if (EPI==0) outb[idx] = f2bf(vv);
        else if (EPI==4) outb[(size_t)col*MROWS + row] = f2bf(vv);
        else             outf[idx] = vv;
      }
    }
}

// ---------------- flash attention: 1 wave/block, 32 q-rows, 32-key chunks ----------------
// q: [M][H] bf16, k: [M][KVD] bf16, vt: [KVD][M] bf16 (transposed), mask: [B][S] f32
__global__ __launch_bounds__(64) void attn_kernel(
    const unsigned short* __restrict__ q, const unsigned short* __restrict__ k,
    const unsigned short* __restrict__ vt, const float* __restrict__ mask,
    unsigned short* __restrict__ o)
{
  __shared__ unsigned short P[2][16][40];
  int lane = threadIdx.x;
  int bid = blockIdx.x;
  int qt = bid & 63;              // 64 q-tiles of 32 rows
  int h  = (bid >> 6) & (NH-1);
  int b  = bid >> 10;
  int g  = h >> 2;
  int qcol = h*HD, kcol = g*HD;
  int fr = lane & 15, fq = lane >> 4, fo = fq*8;
  short8 aq[2][2];
  #pragma unroll
  for (int qi=0;qi<2;qi++){
    const unsigned short* qrow = q + (size_t)(b*SS + qt*32 + qi*16 + fr)*H + qcol;
    aq[qi][0] = *(const short8*)(qrow + fo);
    aq[qi][1] = *(const short8*)(qrow + 32 + fo);
  }
  f32x4 oacc[2][4] = {};
  float m[2][4], lsum[2][4];
  #pragma unroll
  for (int qi=0;qi<2;qi++)
    #pragma unroll
    for (int r=0;r<4;r++){ m[qi][r] = -1e30f; lsum[qi][r] = 0.f; }
  const float scale = 0.125f;
  for (int kc=0; kc<SS; kc+=32){
    short8 kb[2][2];
    #pragma unroll
    for (int f=0; f<2; f++){
      const unsigned short* krow = k + (size_t)(b*SS + kc + f*16 + fr)*KVD + kcol;
      kb[f][0] = *(const short8*)(krow + fo);
      kb[f][1] = *(const short8*)(krow + 32 + fo);
    }
    f32x4 sf[2][2] = {};
    #pragma unroll
    for (int qi=0;qi<2;qi++)
      #pragma unroll
      for (int f=0;f<2;f++){
        sf[qi][f] = __builtin_amdgcn_mfma_f32_16x16x32_bf16(aq[qi][0], kb[f][0], sf[qi][f],0,0,0);
        sf[qi][f] = __builtin_amdgcn_mfma_f32_16x16x32_bf16(aq[qi][1], kb[f][1], sf[qi][f],0,0,0);
      }
    float mk0 = mask[b*SS + kc + fr];
    float mk1 = mask[b*SS + kc + 16 + fr];
    #pragma unroll
    for (int qi=0;qi<2;qi++){
      #pragma unroll
      for (int r=0;r<4;r++){
        float s0 = sf[qi][0][r]*scale + mk0;
        float s1 = sf[qi][1][r]*scale + mk1;
        float c = fmaxf(s0, s1);
        #pragma unroll
        for (int off=1; off<16; off<<=1) c = fmaxf(c, __shfl_xor(c, off));
        float mn = fmaxf(m[qi][r], c);
        float al = __expf(m[qi][r]-mn);
        m[qi][r] = mn;
        s0 = __expf(s0-mn);
        s1 = __expf(s1-mn);
        float ps = s0+s1;
        #pragma unroll
        for (int off=1; off<16; off<<=1) ps += __shfl_xor(ps, off);
        lsum[qi][r] = lsum[qi][r]*al + ps;
        #pragma unroll
        for (int dc=0;dc<4;dc++) oacc[qi][dc][r] *= al;
        P[qi][fq*4+r][fr]    = f2bf(s0);
        P[qi][fq*4+r][16+fr] = f2bf(s1);
      }
    }
    __syncthreads();
    short8 pa[2];
    pa[0] = *(const short8*)&P[0][fr][fo];
    pa[1] = *(const short8*)&P[1][fr][fo];
    #pragma unroll
    for (int dc=0; dc<4; dc++){
      short8 vload = *(const short8*)(vt + (size_t)(kcol + dc*16 + fr)*MROWS + b*SS + kc + fo);
      #pragma unroll
      for (int qi=0;qi<2;qi++)
        oacc[qi][dc] = __builtin_amdgcn_mfma_f32_16x16x32_bf16(pa[qi], vload, oacc[qi][dc],0,0,0);
    }
    __syncthreads();
  }
  #pragma unroll
  for (int qi=0;qi<2;qi++)
    #pragma unroll
    for (int dc=0;dc<4;dc++)
      #pragma unroll
      for (int r=0;r<4;r++){
        float val = oacc[qi][dc][r] / lsum[qi][r];
        int row = qt*32 + qi*16 + fq*4 + r;
        o[(size_t)(b*SS + row)*H + qcol + dc*16 + fr] = f2bf(val);
      }
}

extern "C" void kernel_launch(void* const* d_in, const int* in_sizes, int n_in,
                              void* d_out, int out_size, void* d_ws, size_t ws_size,
                              hipStream_t stream)
{
  const int*   ids  = (const int*)  d_in[0];
  const float* mask = (const float*)d_in[1];
  const float* tok  = (const float*)d_in[2];
  const float* pos  = (const float*)d_in[3];
  const float* Wq   = (const float*)d_in[4];
  const float* bq   = (const float*)d_in[5];
  const float* Wk   = (const float*)d_in[6];
  const float* bk   = (const float*)d_in[7];
  const float* Wv   = (const float*)d_in[8];
  const float* bv   = (const float*)d_in[9];
  const float* Wo   = (const float*)d_in[10];
  const float* bo   = (const float*)d_in[11];
  const float* W1   = (const float*)d_in[12];
  const float* b1   = (const float*)d_in[13];
  const float* W2   = (const float*)d_in[14];
  const float* b2   = (const float*)d_in[15];
  const float* ln1g = (const float*)d_in[16];
  const float* ln1b = (const float*)d_in[17];
  const float* ln2g = (const float*)d_in[18];
  const float* ln2b = (const float*)d_in[19];
  const float* lnfg = (const float*)d_in[20];
  const float* lnfb = (const float*)d_in[21];
  const float* Wh   = (const float*)d_in[22];
  float* out = (float*)d_out;

  char* ws = (char*)d_ws;
  float*          x   = (float*)ws;          ws += (size_t)MROWS*H*4;
  unsigned short* hb  = (unsigned short*)ws; ws += (size_t)MROWS*H*2;
  unsigned short* qb  = (unsigned short*)ws; ws += (size_t)MROWS*H*2;
  unsigned short* kb  = (unsigned short*)ws; ws += (size_t)MROWS*KVD*2;
  unsigned short* vtb = (unsigned short*)ws; ws += (size_t)KVD*MROWS*2;
  unsigned short* ob  = (unsigned short*)ws; ws += (size_t)MROWS*H*2;
  unsigned short* f1  = (unsigned short*)ws; ws += (size_t)MROWS*FF*2;
  unsigned short* WqT = (unsigned short*)ws; ws += (size_t)LAYERS*H*H*2;
  unsigned short* WkT = (unsigned short*)ws; ws += (size_t)LAYERS*H*KVD*2;
  unsigned short* WvT = (unsigned short*)ws; ws += (size_t)LAYERS*H*KVD*2;
  unsigned short* WoT = (unsigned short*)ws; ws += (size_t)LAYERS*H*H*2;
  unsigned short* W1T = (unsigned short*)ws; ws += (size_t)LAYERS*H*FF*2;
  unsigned short* W2T = (unsigned short*)ws; ws += (size_t)LAYERS*H*FF*2;
  unsigned short* WhT = (unsigned short*)ws; ws += (size_t)H*VOC*2;

  // weight conversion+transpose (once per call)
  convT_kernel<<<dim3(H/32,   H/32,  LAYERS), 256, 0, stream>>>(Wq, WqT, H, H);
  convT_kernel<<<dim3(KVD/32, H/32,  LAYERS), 256, 0, stream>>>(Wk, WkT, H, KVD);
  convT_kernel<<<dim3(KVD/32, H/32,  LAYERS), 256, 0, stream>>>(Wv, WvT, H, KVD);
  convT_kernel<<<dim3(H/32,   H/32,  LAYERS), 256, 0, stream>>>(Wo, WoT, H, H);
  convT_kernel<<<dim3(FF/32,  H/32,  LAYERS), 256, 0, stream>>>(W1, W1T, H, FF);
  convT_kernel<<<dim3(H/32,   FF/32, LAYERS), 256, 0, stream>>>(W2, W2T, FF, H);
  convT_kernel<<<dim3(VOC/32, H/32,  1),      256, 0, stream>>>(Wh, WhT, H, VOC);

  embed_kernel<<<MROWS, 256, 0, stream>>>(ids, tok, pos, x);
  for (int l=0; l<LAYERS; l++){
    ln_kernel<<<MROWS,256,0,stream>>>(x, ln1g + l*H, ln1b + l*H, hb);
    gemm_bt<0><<<dim3(MROWS/128, H/128),  256,0,stream>>>(hb, WqT + (size_t)l*H*H,   bq + l*H,   nullptr, nullptr, qb,  H,   H);
    gemm_bt<0><<<dim3(MROWS/128, KVD/128),256,0,stream>>>(hb, WkT + (size_t)l*H*KVD, bk + l*KVD, nullptr, nullptr, kb,  KVD, H);
    gemm_bt<4><<<dim3(MROWS/128, KVD/128),256,0,stream>>>(hb, WvT + (size_t)l*H*KVD, bv + l*KVD, nullptr, nullptr, vtb, KVD, H);
    attn_kernel<<<BB*NH*(SS/32), 64, 0, stream>>>(qb, kb, vtb, mask, ob);
    gemm_bt<1><<<dim3(MROWS/128, H/128),  256,0,stream>>>(ob, WoT + (size_t)l*H*H,   bo + l*H,   x, x, nullptr, H, H);
    ln_kernel<<<MROWS,256,0,stream>>>(x, ln2g + l*H, ln2b + l*H, hb);
    gemm_bt<2><<<dim3(MROWS/128, FF/128), 256,0,stream>>>(hb, W1T + (size_t)l*H*FF,  b1 + l*FF,  nullptr, nullptr, f1, FF, H);
    gemm_bt<1><<<dim3(MROWS/128, H/128),  256,0,stream>>>(f1, W2T + (size_t)l*H*FF,  b2 + l*H,   x, x, nullptr, H, FF);
  }
  ln_kernel<<<MROWS,256,0,stream>>>(x, lnfg, lnfb, hb);
  gemm_bt<3><<<dim3(MROWS/128, VOC/128), 256,0,stream>>>(hb, WhT, nullptr, nullptr, out, nullptr, VOC, H);
}